// Round 5
// baseline (37.120 us; speedup 1.0000x reference)
//
#include <hip/hip_runtime.h>
#include <hip/hip_bf16.h>

// Problem constants
#define B_DIM   32768
#define A_DIM   64
#define L_DIM   1024          // K
#define N_COLS  128           // 2*A
#define NBLK    256           // 1 block per CU, 128 rows each

using bf16x8 = __attribute__((ext_vector_type(8))) __bf16;
using f32x4  = __attribute__((ext_vector_type(4))) float;

// ---------------------------------------------------------------------------
// Pre-kernel: convert W [128 x 1024] f32 -> bf16 in MFMA B-fragment order.
// Unit v (16B): nl=v&15, sub=(v>>4)&3, cf=(v>>6)&7, ks=(v>>9)&31
//   holds Wm[n = cf*16+nl][k = ks*32 + sub*8 + i], i=0..7
// Main kernel chunk c (k-half) = units [c*8192, (c+1)*8192).
// ---------------------------------------------------------------------------
__global__ __launch_bounds__(256)
void convert_w_kernel(const float* __restrict__ W, bf16x8* __restrict__ ws) {
    int v   = blockIdx.x * 256 + threadIdx.x;   // 0..16383
    int nl  = v & 15;
    int sub = (v >> 4) & 3;
    int cf  = (v >> 6) & 7;
    int ks  = (v >> 9) & 31;
    int n   = cf * 16 + nl;
    int k   = ks * 32 + sub * 8;
    const float4* wp = (const float4*)(W + (size_t)n * L_DIM + k);
    float4 w0 = wp[0];
    float4 w1 = wp[1];
    bf16x8 u;
    u[0] = (__bf16)w0.x; u[1] = (__bf16)w0.y;
    u[2] = (__bf16)w0.z; u[3] = (__bf16)w0.w;
    u[4] = (__bf16)w1.x; u[5] = (__bf16)w1.y;
    u[6] = (__bf16)w1.z; u[7] = (__bf16)w1.w;
    ws[v] = u;
}

__device__ __forceinline__ bf16x8 cvt8(float4 a, float4 b) {
    bf16x8 u;
    u[0] = (__bf16)a.x; u[1] = (__bf16)a.y; u[2] = (__bf16)a.z; u[3] = (__bf16)a.w;
    u[4] = (__bf16)b.x; u[5] = (__bf16)b.y; u[6] = (__bf16)b.z; u[7] = (__bf16)b.w;
    return u;
}

// ---------------------------------------------------------------------------
// Main kernel: 512 threads = 8 waves. Wave w owns ROWS [16w, 16w+16) x all
// 128 cols (acc = 8 x f32x4 = 32 VGPR). A streams global->reg->MFMA per wave
// with NO barriers. B (bf16 fragment order, 256 KB) staged through LDS in
// two 128 KB half-K chunks (straight lane-contiguous copy, 0 conflicts).
// Only 3 barriers per block. Register prefetch of the first 4 k-steps of
// each chunk bridges the staging barriers.
// ---------------------------------------------------------------------------
__global__ __launch_bounds__(512, 2)
void branched_policy_kernel(const float* __restrict__ F,
                            const float4* __restrict__ Wf,
                            const float* __restrict__ bias,
                            float* __restrict__ out) {
    __shared__ float4 ldsB[8192];   // 128 KB = one half-K of B fragments

    const int tid  = threadIdx.x;
    const int lane = tid & 63;
    const int wave = tid >> 6;
    const int blk  = blockIdx.x;
    const int lcol = lane & 15;     // A-frag row within 16
    const int lsub = lane >> 4;     // k subgroup 0..3

    const int row0 = blk * 128 + wave * 16;
    const float* fp = F + (size_t)(row0 + lcol) * L_DIM + lsub * 8;

    f32x4 acc[8];
    #pragma unroll
    for (int cf = 0; cf < 8; ++cf) acc[cf] = (f32x4){0.f, 0.f, 0.f, 0.f};

    // ---- prefetch A k-steps 0..3 (bridges staging barrier 1) ----
    float4 pa[4][2];
    #pragma unroll
    for (int k = 0; k < 4; ++k) {
        pa[k][0] = *(const float4*)(fp + k * 32);
        pa[k][1] = *(const float4*)(fp + k * 32 + 4);
    }

    // ---- stage B chunk 0 (ks 0..15): straight copy, lane-contiguous ----
    #pragma unroll
    for (int i = 0; i < 16; ++i)
        ldsB[i * 512 + tid] = Wf[i * 512 + tid];
    __syncthreads();

    // ---- compute chunk 0 ----
    #pragma unroll
    for (int k = 0; k < 16; ++k) {
        bf16x8 af;
        if (k < 4) {
            af = cvt8(pa[k][0], pa[k][1]);
        } else {
            float4 a0 = *(const float4*)(fp + k * 32);
            float4 a1 = *(const float4*)(fp + k * 32 + 4);
            af = cvt8(a0, a1);
        }
        #pragma unroll
        for (int cf = 0; cf < 8; ++cf) {
            bf16x8 bf = *(const bf16x8*)&ldsB[(k * 8 + cf) * 64 + lane];
            acc[cf] = __builtin_amdgcn_mfma_f32_16x16x32_bf16(af, bf, acc[cf], 0, 0, 0);
        }
    }

    // ---- prefetch A k-steps 16..19 (bridges barriers 2+3) ----
    #pragma unroll
    for (int k = 0; k < 4; ++k) {
        pa[k][0] = *(const float4*)(fp + (16 + k) * 32);
        pa[k][1] = *(const float4*)(fp + (16 + k) * 32 + 4);
    }

    __syncthreads();   // all waves done reading chunk 0
    // ---- stage B chunk 1 (ks 16..31) ----
    #pragma unroll
    for (int i = 0; i < 16; ++i)
        ldsB[i * 512 + tid] = Wf[8192 + i * 512 + tid];
    __syncthreads();

    // ---- compute chunk 1 ----
    #pragma unroll
    for (int k = 0; k < 16; ++k) {
        bf16x8 af;
        if (k < 4) {
            af = cvt8(pa[k][0], pa[k][1]);
        } else {
            float4 a0 = *(const float4*)(fp + (16 + k) * 32);
            float4 a1 = *(const float4*)(fp + (16 + k) * 32 + 4);
            af = cvt8(a0, a1);
        }
        #pragma unroll
        for (int cf = 0; cf < 8; ++cf) {
            bf16x8 bf = *(const bf16x8*)&ldsB[(k * 8 + cf) * 64 + lane];
            acc[cf] = __builtin_amdgcn_mfma_f32_16x16x32_bf16(af, bf, acc[cf], 0, 0, 0);
        }
    }

    // ---- epilogue: bias + tanh + de-interleave ----
    float* out0 = out;
    float* out1 = out + (size_t)B_DIM * A_DIM;
    #pragma unroll
    for (int cf = 0; cf < 8; ++cf) {
        int   n  = cf * 16 + lcol;
        float bv = bias[n];
        float* obase = ((n & 1) ? out1 : out0) + (n >> 1);
        #pragma unroll
        for (int j = 0; j < 4; ++j) {
            int   orow = row0 + lsub * 4 + j;
            float x = acc[cf][j] + bv;
            float e = __expf(2.0f * x);                 // tanh = 1 - 2/(e^2x+1)
            obase[(size_t)orow * A_DIM] = 1.0f - 2.0f / (e + 1.0f);
        }
    }
}

// ---------------------------------------------------------------------------
// Fallback (v1-style, self-contained) if ws is too small.
// ---------------------------------------------------------------------------
__global__ __launch_bounds__(256, 2)
void fallback_kernel(const float* __restrict__ F,
                     const float* __restrict__ W,
                     const float* __restrict__ bias,
                     float* __restrict__ out) {
    __shared__ bf16x8 ldsB[4096];
    const int tid  = threadIdx.x;
    const int lane = tid & 63;
    const int wave = tid >> 6;
    const int blk  = blockIdx.x;
    const int lcol = lane & 15;
    const int lsub = lane >> 4;
    const int arow = blk * 64 + wave * 16 + lcol;
    const float* Fp = F + (size_t)arow * L_DIM + lsub * 8;

    f32x4 acc[8];
    #pragma unroll
    for (int c = 0; c < 8; ++c) acc[c] = (f32x4){0.f, 0.f, 0.f, 0.f};

    for (int ch = 0; ch < 4; ++ch) {
        __syncthreads();
        #pragma unroll
        for (int i = 0; i < 16; ++i) {
            int v   = i * 256 + tid;
            int nl  = v & 15;
            int sub = (v >> 4) & 3;
            int c   = (v >> 6) & 7;
            int ks  = (v >> 9) & 7;
            int nn  = c * 16 + nl;
            int k   = ch * 256 + ks * 32 + sub * 8;
            const float4* wp = (const float4*)(W + (size_t)nn * L_DIM + k);
            ldsB[v] = cvt8(wp[0], wp[1]);
        }
        __syncthreads();
        #pragma unroll
        for (int ks = 0; ks < 8; ++ks) {
            const float4* ap = (const float4*)(Fp + ch * 256 + ks * 32);
            bf16x8 af = cvt8(ap[0], ap[1]);
            #pragma unroll
            for (int c = 0; c < 8; ++c) {
                bf16x8 bf = ldsB[(ks * 8 + c) * 64 + lane];
                acc[c] = __builtin_amdgcn_mfma_f32_16x16x32_bf16(af, bf, acc[c], 0, 0, 0);
            }
        }
    }

    const int orow0 = blk * 64 + wave * 16 + lsub * 4;
    float* out0 = out;
    float* out1 = out + (size_t)B_DIM * A_DIM;
    #pragma unroll
    for (int c = 0; c < 8; ++c) {
        int   nn  = c * 16 + lcol;
        float bvv = bias[nn];
        float* ob = (nn & 1) ? out1 : out0;
        #pragma unroll
        for (int j = 0; j < 4; ++j) {
            float x = acc[c][j] + bvv;
            float e = __expf(2.0f * x);
            ob[(size_t)(orow0 + j) * A_DIM + (nn >> 1)] = 1.0f - 2.0f / (e + 1.0f);
        }
    }
}

extern "C" void kernel_launch(void* const* d_in, const int* in_sizes, int n_in,
                              void* d_out, int out_size, void* d_ws, size_t ws_size,
                              hipStream_t stream) {
    const float* F    = (const float*)d_in[0];  // [32768, 1024] f32
    const float* W    = (const float*)d_in[1];  // [64, 2, 1024] f32
    const float* bias = (const float*)d_in[2];  // [64, 2] f32
    float* outp       = (float*)d_out;          // [2][32768, 64] f32

    const size_t ws_needed = (size_t)N_COLS * L_DIM * sizeof(__bf16);  // 256 KB

    if (ws_size >= ws_needed) {
        bf16x8* wf = (bf16x8*)d_ws;
        hipLaunchKernelGGL(convert_w_kernel, dim3(64), dim3(256), 0, stream, W, wf);
        hipLaunchKernelGGL(branched_policy_kernel, dim3(NBLK), dim3(512), 0, stream,
                           F, (const float4*)wf, bias, outp);
    } else {
        hipLaunchKernelGGL(fallback_kernel, dim3(B_DIM / 64), dim3(256), 0, stream,
                           F, W, bias, outp);
    }
}